// Round 8
// baseline (57.151 us; speedup 1.0000x reference)
//
#include <hip/hip_runtime.h>
#include <hip/hip_bf16.h>

typedef float f32x4 __attribute__((ext_vector_type(4)));
typedef short short8 __attribute__((ext_vector_type(8)));
typedef int   i32x4  __attribute__((ext_vector_type(4)));

constexpr int IN_F   = 4096;
constexpr int OUT_F  = 11008;
constexpr int WAVES  = 4;              // K-split factor
constexpr int SEG_K  = IN_F / WAVES;   // 1024
constexpr int NITER  = SEG_K / 32;     // 32 iterations
constexpr int NTILES = OUT_F / 16;     // 688

// f32 -> bf16 round-to-nearest-even
__device__ __forceinline__ unsigned short bf16_rne(float f) {
    unsigned u = __builtin_bit_cast(unsigned, f);
    u += 0x7fffu + ((u >> 16) & 1u);
    return (unsigned short)(u >> 16);
}
// int (0..126) -> bf16 exact (<= 7 significant bits)
__device__ __forceinline__ short bf16_from_int(int v) {
    float f = (float)v;
    return (short)(__builtin_bit_cast(unsigned, f) >> 16);
}

// Pre-pass: x (16x4096 f32) -> bf16 once.
__global__ __launch_bounds__(256) void cvt_x_kernel(
    const float* __restrict__ x, unsigned short* __restrict__ xb)
{
    const int i = (blockIdx.x * 256 + threadIdx.x) * 4;
    float4 v = *(const float4*)(x + i);
    ushort4 o;
    o.x = bf16_rne(v.x); o.y = bf16_rne(v.y);
    o.z = bf16_rne(v.z); o.w = bf16_rne(v.w);
    *(ushort4*)(xb + i) = o;
}

// 688 blocks x 256 threads; 4 waves K-split. x fragments hoisted to VGPRs;
// weight loads are NON-TEMPORAL (bypass L2 allocate — the 180MB stream is
// use-once) direct-to-VGPR dwordx4, loop fully unrolled, no LDS/barriers in
// the hot loop so the compiler can pipeline loads deeply.
__global__ __launch_bounds__(256, 3) void Int8Linear_kernel(
    const unsigned short* __restrict__ xb,  // [16][4096] bf16
    const int*   __restrict__ w,            // [11008][4096] int32 (0..126)
    const float* __restrict__ scale,        // [11008]
    const float* __restrict__ bias,         // [11008]
    float*       __restrict__ out)          // [16][11008] f32
{
    const int tid  = threadIdx.x;
    const int wave = tid >> 6;        // 0..3 -> K segment
    const int lane = tid & 63;
    const int m    = lane & 15;       // token row (A) / weight row in tile (B)
    const int g    = lane >> 4;       // k-subgroup (0..3)
    const int n0   = blockIdx.x * 16;

    // Hoist all x A-fragments for this wave's K segment into registers
    // (32 x short8 = 128 VGPR). Full unroll -> static indexing.
    short8 xf[NITER];
    #pragma unroll
    for (int kb = 0; kb < NITER; ++kb)
        xf[kb] = *(const short8*)(xb + (size_t)m * IN_F + wave * SEG_K + kb * 32 + g * 8);

    const int* wp0 = w + (size_t)(n0 + m) * IN_F + wave * SEG_K + g * 8;

    f32x4 acc = {0.f, 0.f, 0.f, 0.f};

    #pragma unroll
    for (int kb = 0; kb < NITER; ++kb) {
        const i32x4* wp = (const i32x4*)(wp0 + kb * 32);
        i32x4 wa = __builtin_nontemporal_load(wp);
        i32x4 wb = __builtin_nontemporal_load(wp + 1);

        short8 b;
        b[0] = bf16_from_int(wa[0]); b[1] = bf16_from_int(wa[1]);
        b[2] = bf16_from_int(wa[2]); b[3] = bf16_from_int(wa[3]);
        b[4] = bf16_from_int(wb[0]); b[5] = bf16_from_int(wb[1]);
        b[6] = bf16_from_int(wb[2]); b[7] = bf16_from_int(wb[3]);

        acc = __builtin_amdgcn_mfma_f32_16x16x32_bf16(xf[kb], b, acc, 0, 0, 0);
    }

    // Cross-wave K reduction in LDS, fused scale+bias epilogue.
    __shared__ float red[WAVES][16][16];
    #pragma unroll
    for (int r = 0; r < 4; ++r)
        red[wave][g * 4 + r][m] = acc[r];   // row=(lane>>4)*4+r (token), col=lane&15
    __syncthreads();

    const int row = tid >> 4;   // token 0..15
    const int col = tid & 15;
    float s = red[0][row][col] + red[1][row][col]
            + red[2][row][col] + red[3][row][col];
    const int o = n0 + col;
    out[(size_t)row * OUT_F + o] = s * scale[o] + bias[o];
}

extern "C" void kernel_launch(void* const* d_in, const int* in_sizes, int n_in,
                              void* d_out, int out_size, void* d_ws, size_t ws_size,
                              hipStream_t stream) {
    const float* x     = (const float*)d_in[0];
    const int*   w     = (const int*)d_in[1];
    const float* scale = (const float*)d_in[2];
    const float* bias  = (const float*)d_in[3];
    float*       out   = (float*)d_out;
    unsigned short* xb = (unsigned short*)d_ws;   // 128 KB

    cvt_x_kernel<<<64, 256, 0, stream>>>(x, xb);
    Int8Linear_kernel<<<NTILES, 256, 0, stream>>>(xb, w, scale, bias, out);
}

// Round 10
// 48.616 us; speedup vs baseline: 1.1756x; 1.1756x over previous
//
#include <hip/hip_runtime.h>
#include <hip/hip_bf16.h>

typedef float f32x4 __attribute__((ext_vector_type(4)));
typedef short short8 __attribute__((ext_vector_type(8)));

constexpr int IN_F   = 4096;
constexpr int OUT_F  = 11008;
constexpr int WAVES  = 4;              // K-split factor
constexpr int SEG_K  = IN_F / WAVES;   // 1024
constexpr int NITER  = SEG_K / 32;     // 32
constexpr int NTILES = OUT_F / 16;     // 688

// Pack two f32 -> two bf16 (RNE) in one word: v_cvt_pk_bf16_f32 (no builtin
// on gfx950 -> inline asm; lo -> bits[15:0], hi -> bits[31:16]).
__device__ __forceinline__ unsigned cvt2(float lo, float hi) {
    unsigned r;
    asm("v_cvt_pk_bf16_f32 %0, %1, %2" : "=v"(r) : "v"(lo), "v"(hi));
    return r;
}

// Single fused kernel: 688 blocks x 256 threads, 4 waves K-split (R3's proven
// structure). x read as f32 in-loop (256KB, L2-resident) and converted with
// v_cvt_pk_bf16_f32; weights int32 (0..126, exact in bf16) likewise. No
// prepass dispatch, no workspace.
__global__ __launch_bounds__(256, 4) void Int8Linear_kernel(
    const float* __restrict__ x,      // [16][4096] f32
    const int*   __restrict__ w,      // [11008][4096] int32 (0..126)
    const float* __restrict__ scale,  // [11008]
    const float* __restrict__ bias,   // [11008]
    float*       __restrict__ out)    // [16][11008] f32
{
    const int tid  = threadIdx.x;
    const int wave = tid >> 6;        // 0..3 -> K segment
    const int lane = tid & 63;
    const int m    = lane & 15;       // token row (A) / weight row in tile (B)
    const int g    = lane >> 4;       // k-subgroup (0..3), 8 elems
    const int n0   = blockIdx.x * 16;

    const float* xp = x + (size_t)m * IN_F + wave * SEG_K + g * 8;
    const int*   wp = w + (size_t)(n0 + m) * IN_F + wave * SEG_K + g * 8;

    f32x4 acc = {0.f, 0.f, 0.f, 0.f};

    union Pack { short8 s8; unsigned u[4]; };

    #pragma unroll 8
    for (int kb = 0; kb < NITER; ++kb) {
        float4 xa  = *(const float4*)xp;      // 4 f32 of x
        float4 xbv = *(const float4*)(xp + 4);
        int4   wa  = *(const int4*)wp;        // 4 int32 weights
        int4   wb  = *(const int4*)(wp + 4);
        xp += 32; wp += 32;

        Pack a, b;
        a.u[0] = cvt2(xa.x, xa.y);   a.u[1] = cvt2(xa.z, xa.w);
        a.u[2] = cvt2(xbv.x, xbv.y); a.u[3] = cvt2(xbv.z, xbv.w);

        b.u[0] = cvt2((float)wa.x, (float)wa.y);
        b.u[1] = cvt2((float)wa.z, (float)wa.w);
        b.u[2] = cvt2((float)wb.x, (float)wb.y);
        b.u[3] = cvt2((float)wb.z, (float)wb.w);

        acc = __builtin_amdgcn_mfma_f32_16x16x32_bf16(a.s8, b.s8, acc, 0, 0, 0);
    }

    // Cross-wave K reduction in LDS, fused scale+bias epilogue.
    __shared__ float red[WAVES][16][16];
    #pragma unroll
    for (int r = 0; r < 4; ++r)
        red[wave][g * 4 + r][m] = acc[r];   // row=(lane>>4)*4+r (token), col=lane&15
    __syncthreads();

    const int row = tid >> 4;   // token 0..15
    const int col = tid & 15;
    float s = red[0][row][col] + red[1][row][col]
            + red[2][row][col] + red[3][row][col];
    const int o = n0 + col;
    out[(size_t)row * OUT_F + o] = s * scale[o] + bias[o];
}

extern "C" void kernel_launch(void* const* d_in, const int* in_sizes, int n_in,
                              void* d_out, int out_size, void* d_ws, size_t ws_size,
                              hipStream_t stream) {
    const float* x     = (const float*)d_in[0];
    const int*   w     = (const int*)d_in[1];
    const float* scale = (const float*)d_in[2];
    const float* bias  = (const float*)d_in[3];
    float*       out   = (float*)d_out;

    Int8Linear_kernel<<<NTILES, 256, 0, stream>>>(x, w, scale, bias, out);
}

// Round 11
// 43.842 us; speedup vs baseline: 1.3036x; 1.1089x over previous
//
#include <hip/hip_runtime.h>
#include <hip/hip_bf16.h>

typedef float f32x4 __attribute__((ext_vector_type(4)));
typedef short short8 __attribute__((ext_vector_type(8)));

constexpr int IN_F   = 4096;
constexpr int OUT_F  = 11008;
constexpr int WAVES  = 8;              // K-split factor
constexpr int SEG_K  = IN_F / WAVES;   // 512
constexpr int NITER  = SEG_K / 32;     // 16
constexpr int NTILES = OUT_F / 16;     // 688

// f32 -> bf16 round-to-nearest-even
__device__ __forceinline__ unsigned short bf16_rne(float f) {
    unsigned u = __builtin_bit_cast(unsigned, f);
    u += 0x7fffu + ((u >> 16) & 1u);
    return (unsigned short)(u >> 16);
}
// int (0..126) -> bf16 exact (<= 7 significant bits)
__device__ __forceinline__ short bf16_from_int(int v) {
    float f = (float)v;
    return (short)(__builtin_bit_cast(unsigned, f) >> 16);
}

// Pre-pass: x (16x4096 f32) -> bf16 once.
__global__ __launch_bounds__(256) void cvt_x_kernel(
    const float* __restrict__ x, unsigned short* __restrict__ xb)
{
    const int i = (blockIdx.x * 256 + threadIdx.x) * 4;
    float4 v = *(const float4*)(x + i);
    ushort4 o;
    o.x = bf16_rne(v.x); o.y = bf16_rne(v.y);
    o.z = bf16_rne(v.z); o.w = bf16_rne(v.w);
    *(ushort4*)(xb + i) = o;
}

// 688 blocks x 512 threads; 8 waves K-split. ALL x fragments hoisted into
// registers before the loop (16 x short8 = 64 VGPR) so the hot loop's VMEM
// stream is weights ONLY — no L2-hit x reads competing for the load-return
// path. Plain cached loads, compiler-scheduled, no barriers in the loop.
__global__ __launch_bounds__(512, 2) void Int8Linear_kernel(
    const unsigned short* __restrict__ xb,  // [16][4096] bf16
    const int*   __restrict__ w,            // [11008][4096] int32 (0..126)
    const float* __restrict__ scale,        // [11008]
    const float* __restrict__ bias,         // [11008]
    float*       __restrict__ out)          // [16][11008] f32
{
    const int tid  = threadIdx.x;
    const int wave = tid >> 6;        // 0..7 -> K segment
    const int lane = tid & 63;
    const int m    = lane & 15;       // token row (A) / weight row in tile (B)
    const int g    = lane >> 4;       // k-subgroup (0..3)
    const int n0   = blockIdx.x * 16;

    // Hoist this wave's x A-fragments into registers (fully unrolled -> static
    // indices -> registers, rule #20).
    short8 xf[NITER];
    #pragma unroll
    for (int kb = 0; kb < NITER; ++kb)
        xf[kb] = *(const short8*)(xb + (size_t)m * IN_F + wave * SEG_K + kb * 32 + g * 8);

    const int* wp0 = w + (size_t)(n0 + m) * IN_F + wave * SEG_K + g * 8;

    f32x4 acc = {0.f, 0.f, 0.f, 0.f};

    #pragma unroll
    for (int kb = 0; kb < NITER; ++kb) {
        const int* wp = wp0 + kb * 32;
        int4 wa = *(const int4*)wp;
        int4 wb = *(const int4*)(wp + 4);

        short8 b;
        b[0] = bf16_from_int(wa.x); b[1] = bf16_from_int(wa.y);
        b[2] = bf16_from_int(wa.z); b[3] = bf16_from_int(wa.w);
        b[4] = bf16_from_int(wb.x); b[5] = bf16_from_int(wb.y);
        b[6] = bf16_from_int(wb.z); b[7] = bf16_from_int(wb.w);

        acc = __builtin_amdgcn_mfma_f32_16x16x32_bf16(xf[kb], b, acc, 0, 0, 0);
    }

    // Cross-wave K reduction in LDS, fused scale+bias epilogue.
    __shared__ float red[WAVES][16][16];
    #pragma unroll
    for (int r = 0; r < 4; ++r)
        red[wave][g * 4 + r][m] = acc[r];   // row=(lane>>4)*4+r (token), col=lane&15
    __syncthreads();

    if (tid < 256) {
        const int row = tid >> 4;   // token 0..15
        const int col = tid & 15;
        float s = 0.f;
        #pragma unroll
        for (int v = 0; v < WAVES; ++v)
            s += red[v][row][col];
        const int o = n0 + col;
        out[(size_t)row * OUT_F + o] = s * scale[o] + bias[o];
    }
}

extern "C" void kernel_launch(void* const* d_in, const int* in_sizes, int n_in,
                              void* d_out, int out_size, void* d_ws, size_t ws_size,
                              hipStream_t stream) {
    const float* x     = (const float*)d_in[0];
    const int*   w     = (const int*)d_in[1];
    const float* scale = (const float*)d_in[2];
    const float* bias  = (const float*)d_in[3];
    float*       out   = (float*)d_out;
    unsigned short* xb = (unsigned short*)d_ws;   // 128 KB

    cvt_x_kernel<<<64, 256, 0, stream>>>(x, xb);
    Int8Linear_kernel<<<NTILES, 512, 0, stream>>>(xb, w, scale, bias, out);
}

// Round 12
// 43.736 us; speedup vs baseline: 1.3067x; 1.0024x over previous
//
#include <hip/hip_runtime.h>
#include <hip/hip_bf16.h>

typedef float f32x4 __attribute__((ext_vector_type(4)));
typedef short short8 __attribute__((ext_vector_type(8)));

constexpr int IN_F    = 4096;
constexpr int OUT_F   = 11008;
constexpr int NTILES  = OUT_F / 16;    // 688
constexpr int WAVES   = 8;             // K-split within block
constexpr int SEG_K   = IN_F / WAVES;  // 512
constexpr int NITER   = SEG_K / 32;    // 16
constexpr int NBLOCKS = 256;           // persistent, ~1/CU, work-stealing

// f32 -> bf16 round-to-nearest-even
__device__ __forceinline__ unsigned short bf16_rne(float f) {
    unsigned u = __builtin_bit_cast(unsigned, f);
    u += 0x7fffu + ((u >> 16) & 1u);
    return (unsigned short)(u >> 16);
}
// int (0..126) -> bf16 exact (<= 7 significant bits)
__device__ __forceinline__ short bf16_from_int(int v) {
    float f = (float)v;
    return (short)(__builtin_bit_cast(unsigned, f) >> 16);
}

// Pre-pass: x (16x4096 f32) -> bf16 once.
__global__ __launch_bounds__(256) void cvt_x_kernel(
    const float* __restrict__ x, unsigned short* __restrict__ xb)
{
    const int i = (blockIdx.x * 256 + threadIdx.x) * 4;
    float4 v = *(const float4*)(x + i);
    ushort4 o;
    o.x = bf16_rne(v.x); o.y = bf16_rne(v.y);
    o.z = bf16_rne(v.z); o.w = bf16_rne(v.w);
    *(ushort4*)(xb + i) = o;
}

// 256 persistent blocks x 512 threads (8 waves). Each block: static first
// tile = blockIdx.x, then dynamic stealing via global atomic counter.
// Per-CU read bytes self-balance to ~avg (703KB) instead of ceil-quantized
// 768KB — harvests the 9% tail under the per-CU MSHR-rate cap.
// x fragments are tile-independent -> hoisted ONCE into registers.
__global__ __launch_bounds__(512, 2) void Int8Linear_kernel(
    const unsigned short* __restrict__ xb,  // [16][4096] bf16
    const int*   __restrict__ w,            // [11008][4096] int32 (0..126)
    const float* __restrict__ scale,        // [11008]
    const float* __restrict__ bias,         // [11008]
    float*       __restrict__ out,          // [16][11008] f32
    unsigned*    __restrict__ counter)      // zeroed per call
{
    const int tid  = threadIdx.x;
    const int wave = tid >> 6;        // 0..7 -> K segment
    const int lane = tid & 63;
    const int m    = lane & 15;       // token row (A) / weight row in tile (B)
    const int g    = lane >> 4;       // k-subgroup (0..3)

    __shared__ float red[WAVES][16][16];
    __shared__ unsigned s_t;

    // Hoist this wave's x A-fragments once (tile-independent); 16 x short8
    // = 64 VGPR, fully unrolled -> static indices -> registers.
    short8 xf[NITER];
    #pragma unroll
    for (int kb = 0; kb < NITER; ++kb)
        xf[kb] = *(const short8*)(xb + (size_t)m * IN_F + wave * SEG_K + kb * 32 + g * 8);

    int t = blockIdx.x;   // static first tile
    while (t < NTILES) {
        const int n0  = t * 16;
        const int* wp0 = w + (size_t)(n0 + m) * IN_F + wave * SEG_K + g * 8;

        f32x4 acc = {0.f, 0.f, 0.f, 0.f};
        #pragma unroll
        for (int kb = 0; kb < NITER; ++kb) {
            const int* wp = wp0 + kb * 32;
            int4 wa = *(const int4*)wp;
            int4 wb = *(const int4*)(wp + 4);

            short8 b;
            b[0] = bf16_from_int(wa.x); b[1] = bf16_from_int(wa.y);
            b[2] = bf16_from_int(wa.z); b[3] = bf16_from_int(wa.w);
            b[4] = bf16_from_int(wb.x); b[5] = bf16_from_int(wb.y);
            b[6] = bf16_from_int(wb.z); b[7] = bf16_from_int(wb.w);

            acc = __builtin_amdgcn_mfma_f32_16x16x32_bf16(xf[kb], b, acc, 0, 0, 0);
        }

        // Steal next tile early; atomic latency hides under the reduction.
        if (tid == 0) s_t = NBLOCKS + atomicAdd(counter, 1u);

        #pragma unroll
        for (int r = 0; r < 4; ++r)
            red[wave][g * 4 + r][m] = acc[r];   // row=(lane>>4)*4+r, col=lane&15
        __syncthreads();

        if (tid < 256) {
            const int row = tid >> 4;   // token 0..15
            const int col = tid & 15;
            float s = 0.f;
            #pragma unroll
            for (int v = 0; v < WAVES; ++v)
                s += red[v][row][col];
            const int o = n0 + col;
            out[(size_t)row * OUT_F + o] = s * scale[o] + bias[o];
        }

        t = (int)s_t;          // valid: written before the first barrier
        __syncthreads();       // red/s_t safe to overwrite next iteration
    }
}

extern "C" void kernel_launch(void* const* d_in, const int* in_sizes, int n_in,
                              void* d_out, int out_size, void* d_ws, size_t ws_size,
                              hipStream_t stream) {
    const float* x     = (const float*)d_in[0];
    const int*   w     = (const int*)d_in[1];
    const float* scale = (const float*)d_in[2];
    const float* bias  = (const float*)d_in[3];
    float*       out   = (float*)d_out;

    unsigned*       counter = (unsigned*)d_ws;                 // 4 B @ offset 0
    unsigned short* xb      = (unsigned short*)((char*)d_ws + 512);  // 128 KB

    hipMemsetAsync(counter, 0, sizeof(unsigned), stream);
    cvt_x_kernel<<<64, 256, 0, stream>>>(x, xb);
    Int8Linear_kernel<<<NBLOCKS, 512, 0, stream>>>(xb, w, scale, bias, out, counter);
}